// Round 8
// baseline (193.761 us; speedup 1.0000x reference)
//
#include <hip/hip_runtime.h>
#include <hip/hip_bf16.h>
#include <stdint.h>

#define BATCH 256
#define PFD 128
#define T1 129
#define NPAIRS 1089      // 33*33
#define BK 32            // k-rows per LDS tile
#define CHUNK 4
#define AVSTR 5          // av_lds row stride (floats)
#define SMAX 512

typedef short bf16x8 __attribute__((ext_vector_type(8)));
typedef float f32x4 __attribute__((ext_vector_type(4)));

static __device__ __forceinline__ float float_of(unsigned u){ union{float f;unsigned u;}x;x.u=u;return x.f; }
static __device__ __forceinline__ unsigned pk_bf16(float a, float b){
  union { __hip_bfloat162 h; unsigned u; } c;
  c.h = __float22bfloat162_rn(make_float2(a, b));
  return c.u;
}

// async global->LDS, 16B per lane; lds dest = wave-uniform base + lane*16
static __device__ __forceinline__ void gld_lds16(const float* gp, float* lp) {
  __builtin_amdgcn_global_load_lds(
      (const __attribute__((address_space(1))) unsigned*)gp,
      (__attribute__((address_space(3))) unsigned*)lp, 16, 0, 0);
}

// ---------------- Kernel 1: split-K fused trilinear GEMM ----------------
// S blocks x 512 thr, 2 blocks/CU (LDS 37 KB, VGPR ~120). Block owns 2-3
// (ia,iv) pairs. k-slot q of pair p <-> W1 row q+1 (t = text[q]); W1 row 0
// (ones row) folded as rank-1 VALU update. W1 fp32 tiles (32k x 128n) staged
// via global_load_lds dwordx4 into LDS double buffer; ONE barrier per tile,
// stage(s+1) issued after the barrier so loads fly during compute(s).
__global__ __launch_bounds__(512, 2) void tfn_k1(
    const float* __restrict__ audio, const float* __restrict__ video,
    const float* __restrict__ text, const float* __restrict__ W1,
    unsigned short* __restrict__ part, int S) {
  __shared__ __align__(16) float b_lds[2][BK * PFD];   // 2 x 16384 B
  __shared__ float av_lds[BATCH * AVSTR];              // 5120 B

  const int tid = threadIdx.x;
  const int bk = blockIdx.x;
  const int npb = NPAIRS / S, rem0 = NPAIRS % S;
  const int p0 = bk * npb + (bk < rem0 ? bk : rem0);
  const int np = npb + (bk < rem0 ? 1 : 0);

  const int wave = tid >> 6, lane = tid & 63;
  const int l15 = lane & 15, quad = lane >> 4;
  const int mrow0 = (wave & 3) * 64, nseg = (wave >> 2) * 64;

  f32x4 acc[4][4];
  #pragma unroll
  for (int a = 0; a < 4; ++a)
    #pragma unroll
    for (int b = 0; b < 4; ++b) acc[a][b] = f32x4{0.f, 0.f, 0.f, 0.f};

  for (int c0 = 0; c0 < np; c0 += CHUNK) {
    const int nc = (np - c0) < CHUNK ? (np - c0) : CHUNK;
    const int pbase = p0 + c0;
    if (c0) __syncthreads();             // protect av_lds rewrite
    {  // av for this chunk's pairs
      const int m = tid & 127, jh = tid >> 7;   // jh in 0..3 -> pair slot
      float avv = 0.0f;
      if (jh < nc) {
        int p = pbase + jh;
        int ia = p / 33, iv = p - ia * 33;
        float a = (ia == 0) ? 1.0f : audio[m * 32 + ia - 1];
        float v = (iv == 0) ? 1.0f : video[m * 32 + iv - 1];
        avv = a * v;
      }
      av_lds[m * AVSTR + jh] = avv;
      const int m2 = m + 128;
      float avv2 = 0.0f;
      if (jh < nc) {
        int p = pbase + jh;
        int ia = p / 33, iv = p - ia * 33;
        float a = (ia == 0) ? 1.0f : audio[m2 * 32 + ia - 1];
        float v = (iv == 0) ? 1.0f : video[m2 * 32 + iv - 1];
        avv2 = a * v;
      }
      av_lds[m2 * AVSTR + jh] = avv2;
    }
    const int ntiles = nc * 4;           // 4 tiles of 32 rows per pair
    // prime: stage tile 0 -> buf 0
    {
      const float* gt = W1 + ((size_t)pbase * T1 + 1) * PFD;
      gld_lds16(gt + tid * 4, &b_lds[0][tid * 4]);
      gld_lds16(gt + tid * 4 + 2048, &b_lds[0][tid * 4 + 2048]);
    }
    for (int s = 0; s < ntiles; ++s) {
      __syncthreads();   // drains loads for tile s; compute(s-1) done -> buf (s+1)&1 free
      if (s + 1 < ntiles) {
        const int jp1 = (s + 1) >> 2, kq1 = (s + 1) & 3;
        const float* gt = W1 + ((size_t)(pbase + jp1) * T1 + 1 + kq1 * BK) * PFD;
        float* lb = &b_lds[(s + 1) & 1][0];
        gld_lds16(gt + tid * 4, lb + tid * 4);
        gld_lds16(gt + tid * 4 + 2048, lb + tid * 4 + 2048);
      }
      // compute tile s
      const int jp = s >> 2, kq = s & 3;
      const float* lb = &b_lds[s & 1][0];
      // A fragments: av * t, packed bf16
      bf16x8 A[4];
      #pragma unroll
      for (int mt = 0; mt < 4; ++mt) {
        const int m = mrow0 + mt * 16 + l15;
        const float avv = av_lds[m * AVSTR + jp];
        const float4 ta = *(const float4*)&text[m * PFD + kq * 32 + quad * 8];
        const float4 tb = *(const float4*)&text[m * PFD + kq * 32 + quad * 8 + 4];
        union { bf16x8 v; unsigned u[4]; } c;
        c.u[0] = pk_bf16(avv * ta.x, avv * ta.y);
        c.u[1] = pk_bf16(avv * ta.z, avv * ta.w);
        c.u[2] = pk_bf16(avv * tb.x, avv * tb.y);
        c.u[3] = pk_bf16(avv * tb.z, avv * tb.w);
        A[mt] = c.v;
      }
      #pragma unroll
      for (int nt = 0; nt < 4; ++nt) {
        const int n = nseg + nt * 16 + l15;
        float bb[8];
        #pragma unroll
        for (int j = 0; j < 8; ++j) bb[j] = lb[(quad * 8 + j) * PFD + n];
        union { bf16x8 v; unsigned u[4]; } c;
        #pragma unroll
        for (int d = 0; d < 4; ++d) c.u[d] = pk_bf16(bb[2 * d], bb[2 * d + 1]);
        #pragma unroll
        for (int mt = 0; mt < 4; ++mt)
          acc[mt][nt] = __builtin_amdgcn_mfma_f32_16x16x32_bf16(A[mt], c.v, acc[mt][nt], 0, 0, 0);
      }
    }
    // ones-row (W1 row 0, t=1) rank-1 updates, C-layout
    for (int jp = 0; jp < nc; ++jp) {
      const float* Wp = W1 + (size_t)(pbase + jp) * (T1 * PFD);
      float w0[4];
      #pragma unroll
      for (int nt = 0; nt < 4; ++nt) w0[nt] = Wp[nseg + nt * 16 + l15];
      #pragma unroll
      for (int mt = 0; mt < 4; ++mt) {
        #pragma unroll
        for (int r = 0; r < 4; ++r) {
          const float avt = av_lds[(mrow0 + mt * 16 + quad * 4 + r) * AVSTR + jp];
          #pragma unroll
          for (int nt = 0; nt < 4; ++nt)
            acc[mt][nt][r] += avt * w0[nt];
        }
      }
    }
  }

  // writeback: bf16, m-major [m][S][phys]; phys-in-seg = l15*4 + nt
  #pragma unroll
  for (int mt = 0; mt < 4; ++mt)
    #pragma unroll
    for (int r = 0; r < 4; ++r) {
      const int m = mrow0 + mt * 16 + quad * 4 + r;
      uint2 w;
      w.x = pk_bf16(acc[mt][0][r], acc[mt][1][r]);
      w.y = pk_bf16(acc[mt][2][r], acc[mt][3][r]);
      *(uint2*)&part[((size_t)m * S + bk) * PFD + nseg + l15 * 4] = w;
    }
}

// ---------------- Kernel 2: contiguous reduce + bias/relu + layers 2,3 ----------------
__global__ __launch_bounds__(256) void tfn_k2(
    const unsigned short* __restrict__ part, const float* __restrict__ b1,
    const float* __restrict__ W2, const float* __restrict__ b2,
    const float* __restrict__ W3, const float* __restrict__ b3,
    float* __restrict__ out, int S) {
  __shared__ float sred[256 * 4];
  __shared__ float h1s[PFD];
  __shared__ float a2s[256];
  __shared__ float red[2];
  const int m = blockIdx.x, tid = threadIdx.x;
  const int g = tid & 31, q = tid >> 5;
  const unsigned short* base = part + (size_t)m * S * PFD;
  float s0 = 0, s1 = 0, s2 = 0, s3 = 0;
  for (int bkk = q; bkk < S; bkk += 8) {
    uint2 v = *(const uint2*)&base[(size_t)bkk * PFD + g * 4];
    s0 += float_of(v.x << 16);
    s1 += float_of(v.x & 0xFFFF0000u);
    s2 += float_of(v.y << 16);
    s3 += float_of(v.y & 0xFFFF0000u);
  }
  sred[tid * 4 + 0] = s0; sred[tid * 4 + 1] = s1;
  sred[tid * 4 + 2] = s2; sred[tid * 4 + 3] = s3;
  __syncthreads();
  if (tid < PFD) {
    const int p = tid;       // phys column
    float h = 0;
    #pragma unroll
    for (int bl = 0; bl < 8; ++bl) h += sred[(bl * 32 + (p >> 2)) * 4 + (p & 3)];
    const int seg = p >> 6, qq = p & 63;
    const int n = seg * 64 + (qq & 3) * 16 + (qq >> 2);   // phys -> logical
    h1s[n] = fmaxf(h + b1[n], 0.0f);
  }
  __syncthreads();
  const int n = tid & 127, half = tid >> 7;
  float a2 = 0.0f;
  const int k0 = half * 64;
  #pragma unroll 8
  for (int k = 0; k < 64; ++k) a2 += h1s[k0 + k] * W2[(k0 + k) * PFD + n];
  a2s[tid] = a2;
  __syncthreads();
  if (half == 0) {
    float h2 = fmaxf(a2s[n] + a2s[n + 128] + b2[n], 0.0f);
    float pr = h2 * W3[n];
    #pragma unroll
    for (int off = 32; off > 0; off >>= 1) pr += __shfl_down(pr, off);
    if ((tid & 63) == 0) red[tid >> 6] = pr;
  }
  __syncthreads();
  if (tid == 0) out[m] = red[0] + red[1] + b3[0];
}

extern "C" void kernel_launch(void* const* d_in, const int* in_sizes, int n_in,
                              void* d_out, int out_size, void* d_ws, size_t ws_size,
                              hipStream_t stream) {
  const float* audio = (const float*)d_in[0];
  const float* video = (const float*)d_in[1];
  const float* text  = (const float*)d_in[2];
  const float* W1 = (const float*)d_in[3];
  const float* b1 = (const float*)d_in[4];
  const float* W2 = (const float*)d_in[5];
  const float* b2 = (const float*)d_in[6];
  const float* W3 = (const float*)d_in[7];
  const float* b3 = (const float*)d_in[8];
  unsigned short* part = (unsigned short*)d_ws;

  const size_t slab = (size_t)BATCH * PFD * sizeof(unsigned short);  // 64 KB
  int S = (int)(ws_size / slab);
  if (S > SMAX) S = SMAX;
  if (S < 1) S = 1;

  tfn_k1<<<S, 512, 0, stream>>>(audio, video, text, W1, part, S);
  tfn_k2<<<BATCH, 256, 0, stream>>>(part, b1, W2, b2, W3, b3, (float*)d_out, S);
}

// Round 9
// 183.095 us; speedup vs baseline: 1.0583x; 1.0583x over previous
//
#include <hip/hip_runtime.h>
#include <hip/hip_bf16.h>
#include <stdint.h>

#define BATCH 256
#define PFD 128
#define T1 129
#define NPAIRS 1089      // 33*33
#define BKSTR 72         // b_lds col stride (bf16 shorts), 144 B
#define CHUNK 5
#define SMAX 256

typedef short bf16x8 __attribute__((ext_vector_type(8)));
typedef float f32x4 __attribute__((ext_vector_type(4)));

static __device__ __forceinline__ float float_of(unsigned u){ union{float f;unsigned u;}x;x.u=u;return x.f; }
static __device__ __forceinline__ unsigned pk_bf16(float a, float b){
  union { __hip_bfloat162 h; unsigned u; } c;
  c.h = __float22bfloat162_rn(make_float2(a, b));
  return c.u;
}

// ---------------- Kernel 1: split-K + split-N fused trilinear GEMM ----------------
// grid = 2*S blocks x 512 thr. Block (sblk, h): pairs of slice sblk, n-cols
// h*64..h*64+63. acc = 32 AGPRs (wave: m32 x n64) -> unified regs ~120 ≤ 128
// -> 2 blocks/CU genuinely co-resident (the TLP that hides barrier drains).
// k-slot q of pair p <-> W1 row q+1 (t = text[q]); ones row (W1 row 0) as
// rank-1 VALU update. W1 staged fp32->VGPR->pack bf16->LDS dbuf; loads for
// tile s+1 issued right after barrier(s-1) so compute(s) covers their latency;
// nothing in flight at each barrier's vmcnt(0) drain.
__global__ __launch_bounds__(512, 4) void tfn_k1(
    const float* __restrict__ audio, const float* __restrict__ video,
    const float* __restrict__ text, const float* __restrict__ W1,
    unsigned short* __restrict__ part, int S) {
  __shared__ __align__(16) short b_lds[2][64 * BKSTR];   // 2 x 9216 B
  __shared__ float av_lds[BATCH * CHUNK];                // 5120 B

  const int tid = threadIdx.x;
  const int bk = blockIdx.x;
  const int sblk = bk >> 1, nbase = (bk & 1) * 64;
  const int npb = NPAIRS / S, rem0 = NPAIRS % S;
  const int p0 = sblk * npb + (sblk < rem0 ? sblk : rem0);
  const int np = npb + (sblk < rem0 ? 1 : 0);

  const int wave = tid >> 6, lane = tid & 63;
  const int l15 = lane & 15, quad = lane >> 4;
  const int mrow0 = wave * 32;            // 8 waves x 32 m-rows
  const int sn6 = tid & 63, skg = tid >> 6;  // staging: col, row-group

  // persistent t in packed bf16, A-layout: treg[mt][ks][d] = t at k-slots
  // ks*32 + quad*8 + {2d,2d+1}   (t at slot q = text[q])
  unsigned treg[2][4][4];
  #pragma unroll
  for (int mt = 0; mt < 2; ++mt) {
    const int m = mrow0 + mt * 16 + l15;
    #pragma unroll
    for (int ks = 0; ks < 4; ++ks) {
      const float4 ta = *(const float4*)&text[m * PFD + ks * 32 + quad * 8];
      const float4 tb = *(const float4*)&text[m * PFD + ks * 32 + quad * 8 + 4];
      treg[mt][ks][0] = pk_bf16(ta.x, ta.y);
      treg[mt][ks][1] = pk_bf16(ta.z, ta.w);
      treg[mt][ks][2] = pk_bf16(tb.x, tb.y);
      treg[mt][ks][3] = pk_bf16(tb.z, tb.w);
    }
  }

  f32x4 acc[2][4];
  #pragma unroll
  for (int a = 0; a < 2; ++a)
    #pragma unroll
    for (int b = 0; b < 4; ++b) acc[a][b] = f32x4{0.f, 0.f, 0.f, 0.f};

  for (int c0 = 0; c0 < np; c0 += CHUNK) {
    const int nc = (np - c0) < CHUNK ? (np - c0) : CHUNK;
    const int pbase = p0 + c0;
    if (c0) __syncthreads();   // prev chunk's av readers done
    {  // stage av for this chunk's pairs
      const int m = tid & 255;
      for (int j = tid >> 8; j < nc; j += 2) {
        int p = pbase + j;
        int ia = p / 33, iv = p - ia * 33;
        float a = (ia == 0) ? 1.0f : audio[m * 32 + ia - 1];
        float v = (iv == 0) ? 1.0f : video[m * 32 + iv - 1];
        av_lds[m * CHUNK + j] = a * v;
      }
    }
    // prime: load + stage tile 0 (pair pbase, k-slots 0..63 -> W1 rows 1..64)
    {
      float pf[8];
      const float* g = W1 + ((size_t)pbase * T1 + 1) * PFD + nbase + sn6;
      #pragma unroll
      for (int j = 0; j < 8; ++j) pf[j] = g[(skg * 8 + j) * PFD];
      union { bf16x8 v; unsigned u[4]; } w;
      #pragma unroll
      for (int d = 0; d < 4; ++d) w.u[d] = pk_bf16(pf[2 * d], pf[2 * d + 1]);
      *(bf16x8*)&b_lds[0][sn6 * BKSTR + skg * 8] = w.v;
    }
    __syncthreads();           // av + buf0 ready
    const int ntiles = nc * 2;
    for (int s = 0; s < ntiles; ++s) {
      const int buf = s & 1;
      // issue tile s+1 loads NOW (latency covered by compute below)
      float nf[8];
      if (s + 1 < ntiles) {
        const int jp1 = (s + 1) >> 1, h1 = (s + 1) & 1;
        const float* g = W1 + ((size_t)(pbase + jp1) * T1 + 1 + h1 * 64) * PFD + nbase + sn6;
        #pragma unroll
        for (int j = 0; j < 8; ++j) nf[j] = g[(skg * 8 + j) * PFD];
      }
      // compute tile s
      const int jp = s >> 1, h2 = s & 1;
      float avf[2];
      avf[0] = av_lds[(mrow0 + l15) * CHUNK + jp];
      avf[1] = av_lds[(mrow0 + 16 + l15) * CHUNK + jp];
      #pragma unroll
      for (int ks2 = 0; ks2 < 2; ++ks2) {
        const int ks = h2 * 2 + ks2;
        bf16x8 A[2];
        #pragma unroll
        for (int mt = 0; mt < 2; ++mt) {
          union { bf16x8 v; unsigned u[4]; } c;
          #pragma unroll
          for (int d = 0; d < 4; ++d) {
            const unsigned t = treg[mt][ks][d];
            c.u[d] = pk_bf16(float_of(t << 16) * avf[mt],
                             float_of(t & 0xFFFF0000u) * avf[mt]);
          }
          A[mt] = c.v;
        }
        #pragma unroll
        for (int nt = 0; nt < 4; ++nt) {
          bf16x8 bf = *(const bf16x8*)&b_lds[buf][(nt * 16 + l15) * BKSTR + ks2 * 32 + quad * 8];
          acc[0][nt] = __builtin_amdgcn_mfma_f32_16x16x32_bf16(A[0], bf, acc[0][nt], 0, 0, 0);
          acc[1][nt] = __builtin_amdgcn_mfma_f32_16x16x32_bf16(A[1], bf, acc[1][nt], 0, 0, 0);
        }
      }
      // stage tile s+1 (waits exactly on nf; latency already covered)
      if (s + 1 < ntiles) {
        union { bf16x8 v; unsigned u[4]; } w;
        #pragma unroll
        for (int d = 0; d < 4; ++d) w.u[d] = pk_bf16(nf[2 * d], nf[2 * d + 1]);
        *(bf16x8*)&b_lds[buf ^ 1][sn6 * BKSTR + skg * 8] = w.v;
      }
      __syncthreads();         // nothing in flight: drain is cheap
    }
    // ones-row (W1 row 0, t = 1): rank-1 update in C-layout
    for (int jp = 0; jp < nc; ++jp) {
      const float* Wp = W1 + (size_t)(pbase + jp) * (T1 * PFD);
      float w0[4];
      #pragma unroll
      for (int nt = 0; nt < 4; ++nt) w0[nt] = Wp[nbase + nt * 16 + l15];
      #pragma unroll
      for (int mt = 0; mt < 2; ++mt)
        #pragma unroll
        for (int r = 0; r < 4; ++r) {
          const float avt = av_lds[(mrow0 + mt * 16 + quad * 4 + r) * CHUNK + jp];
          #pragma unroll
          for (int nt = 0; nt < 4; ++nt)
            acc[mt][nt][r] += avt * w0[nt];
        }
    }
  }

  // writeback: bf16, m-major [m][S][128]; phys col = nbase + l15*4 + nt
  #pragma unroll
  for (int mt = 0; mt < 2; ++mt)
    #pragma unroll
    for (int r = 0; r < 4; ++r) {
      const int m = mrow0 + mt * 16 + quad * 4 + r;
      uint2 w;
      w.x = pk_bf16(acc[mt][0][r], acc[mt][1][r]);
      w.y = pk_bf16(acc[mt][2][r], acc[mt][3][r]);
      *(uint2*)&part[((size_t)m * S + sblk) * PFD + nbase + l15 * 4] = w;
    }
}

// ---------------- Kernel 2: contiguous reduce + bias/relu + layers 2,3 ----------------
__global__ __launch_bounds__(256) void tfn_k2(
    const unsigned short* __restrict__ part, const float* __restrict__ b1,
    const float* __restrict__ W2, const float* __restrict__ b2,
    const float* __restrict__ W3, const float* __restrict__ b3,
    float* __restrict__ out, int S) {
  __shared__ float sred[256 * 4];
  __shared__ float h1s[PFD];
  __shared__ float a2s[256];
  __shared__ float red[2];
  const int m = blockIdx.x, tid = threadIdx.x;
  const int g = tid & 31, q = tid >> 5;
  const unsigned short* base = part + (size_t)m * S * PFD;
  float s0 = 0, s1 = 0, s2 = 0, s3 = 0;
  for (int bkk = q; bkk < S; bkk += 8) {
    uint2 v = *(const uint2*)&base[(size_t)bkk * PFD + g * 4];
    s0 += float_of(v.x << 16);
    s1 += float_of(v.x & 0xFFFF0000u);
    s2 += float_of(v.y << 16);
    s3 += float_of(v.y & 0xFFFF0000u);
  }
  sred[tid * 4 + 0] = s0; sred[tid * 4 + 1] = s1;
  sred[tid * 4 + 2] = s2; sred[tid * 4 + 3] = s3;
  __syncthreads();
  if (tid < PFD) {
    const int p = tid;       // phys column
    float h = 0;
    #pragma unroll
    for (int bl = 0; bl < 8; ++bl) h += sred[(bl * 32 + (p >> 2)) * 4 + (p & 3)];
    const int seg = p >> 6, qq = p & 63;
    const int n = seg * 64 + (qq & 3) * 16 + (qq >> 2);   // phys -> logical
    h1s[n] = fmaxf(h + b1[n], 0.0f);
  }
  __syncthreads();
  const int n = tid & 127, half = tid >> 7;
  float a2 = 0.0f;
  const int k0 = half * 64;
  #pragma unroll 8
  for (int k = 0; k < 64; ++k) a2 += h1s[k0 + k] * W2[(k0 + k) * PFD + n];
  a2s[tid] = a2;
  __syncthreads();
  if (half == 0) {
    float h2 = fmaxf(a2s[n] + a2s[n + 128] + b2[n], 0.0f);
    float pr = h2 * W3[n];
    #pragma unroll
    for (int off = 32; off > 0; off >>= 1) pr += __shfl_down(pr, off);
    if ((tid & 63) == 0) red[tid >> 6] = pr;
  }
  __syncthreads();
  if (tid == 0) out[m] = red[0] + red[1] + b3[0];
}

extern "C" void kernel_launch(void* const* d_in, const int* in_sizes, int n_in,
                              void* d_out, int out_size, void* d_ws, size_t ws_size,
                              hipStream_t stream) {
  const float* audio = (const float*)d_in[0];
  const float* video = (const float*)d_in[1];
  const float* text  = (const float*)d_in[2];
  const float* W1 = (const float*)d_in[3];
  const float* b1 = (const float*)d_in[4];
  const float* W2 = (const float*)d_in[5];
  const float* b2 = (const float*)d_in[6];
  const float* W3 = (const float*)d_in[7];
  const float* b3 = (const float*)d_in[8];
  unsigned short* part = (unsigned short*)d_ws;

  const size_t slab = (size_t)BATCH * PFD * sizeof(unsigned short);  // 64 KB
  int S = (int)(ws_size / slab);
  if (S > SMAX) S = SMAX;
  if (S < 1) S = 1;

  tfn_k1<<<2 * S, 512, 0, stream>>>(audio, video, text, W1, part, S);
  tfn_k2<<<BATCH, 256, 0, stream>>>(part, b1, W2, b2, W3, b3, (float*)d_out, S);
}